// Round 8
// baseline (215.939 us; speedup 1.0000x reference)
//
#include <hip/hip_runtime.h>
#include <hip/hip_fp16.h>

// 2-layer GCN via CSR gather built by a two-level counting sort with
// fixed-capacity (padded) coarse buckets:
//   k_init_gcur: gcur[b] = b*CAP
//   k_partition: LDS coarse hist -> scan -> rank tile into LDS-sorted order ->
//                linear coalesced emit (no per-element atomics on the emit)
//   k_bucket:    1024 thr, edges staged once into LDS ev[]; fine hist+scan+place
//                -> ssrc/beg/end/dis (single global read of ebuf)
//   k_gemm1:     g = fp16(dis * (x@W1)), 8 lanes/row
//   k_gather1:   2 lanes/node, 16B (float4 = 8 fp16) gather (unroll x8) + relu
//                + dot(W2) -> t
//   k_gather2:   8 lanes/node scalar gather (unroll x4) -> out
// R8 lesson: per-edge fp32 LDS atomics (ds_add) are ~6x slower than sorted-gather.
// R9 lesson: per-thread sequential row reads are line-complete; gemm1 loads were
// never the bottleneck.
// R10 lesson (counters): nt-store on SCATTERED 4B writes defeats L2 write-
// combining -> 148MB HBM for a 13MB array; k_bucket 80us. nt reverted.
// R11-R14 lesson (measured 214us): nt-revert confirmed (k_bucket left top-5,
// i.e. <41us); 4-lane gather1 was NEUTRAL vs the 8-lane 210us baseline -> not
// purely VMEM-issue-bound. Top-5 is all harness fill/reset dispatches (~41us),
// so every kernel is now <41us; per-kernel counters invisible below that line.
// R15: gather1 at 2 lanes/node with float4 16B loads — halves VMEM instrs AND
// halves L2 sector traffic (random requests cost a 64B sector each: 12.8M x
// 8B = 819MB -> 6.4M x 16B = 410MB). Rows are 32B-aligned so a 16B load never
// straddles a 128B line. Predicted 214 -> ~195us; if neutral, gather1 is
// latency-bound and the lever moves to the sort kernels; if >220us, revert to
// 4-lane (TLP dropped to ~6 waves/CU).
// R16, R17: identical resubmits — R15/R16 benches died on broker timeout
// (5 infra failures in 7 rounds); no counters; do not stack untested changes.

#define CB 8                  // coarse bucket = col >> CB (256 nodes/bucket)
#define CAP 9216              // max edges per bucket (mean 8192 + 11 sigma)
#define TILE 4096             // edges per partition block (512 thr x 8)

__global__ void k_init_gcur(int* __restrict__ gcur, int nb) {
    int b = blockIdx.x * blockDim.x + threadIdx.x;
    if (b < nb) gcur[b] = b * CAP;
}

// Pack (col&255)<<17 | row  (row < 2^17).
__global__ void __launch_bounds__(512) k_partition(
        const int* __restrict__ row, const int* __restrict__ col,
        int* __restrict__ gcur, int* __restrict__ ebuf, int e, int nb) {
    __shared__ int hist[512];            // counts -> local cursor
    __shared__ int lbase[512];           // exclusive scan (local base)
    __shared__ int gdelta[512];          // gbase[b] - lbase[b]
    __shared__ int sval[TILE];           // tile sorted by bucket
    __shared__ unsigned short sbkt[TILE];
    const int base = blockIdx.x * TILE;
    const int cnt = min(TILE, e - base);
    const int t = threadIdx.x;
    hist[t] = 0;
    __syncthreads();
#pragma unroll
    for (int k = 0; k < TILE / 512; ++k) {
        int i = base + (k << 9) + t;
        if (i < e) atomicAdd(&hist[col[i] >> CB], 1);
    }
    __syncthreads();
    int v = hist[t];
    lbase[t] = v;
    __syncthreads();
    for (int off = 1; off < 512; off <<= 1) {
        int add = (t >= off) ? lbase[t - off] : 0;
        __syncthreads();
        lbase[t] += add;
        __syncthreads();
    }
    int excl = lbase[t] - v;
    __syncthreads();
    lbase[t] = excl;
    int gb = v ? atomicAdd(&gcur[t], v) : 0;   // t >= nb has v == 0
    gdelta[t] = gb - excl;
    hist[t] = excl;                            // local rank cursor
    __syncthreads();
#pragma unroll
    for (int k = 0; k < TILE / 512; ++k) {
        int i = base + (k << 9) + t;
        if (i < e) {
            int c = col[i], r = row[i];
            int b = c >> CB;
            int p = atomicAdd(&hist[b], 1);
            sval[p] = ((c & ((1 << CB) - 1)) << 17) | r;
            sbkt[p] = (unsigned short)b;
        }
    }
    __syncthreads();
    for (int j = t; j < cnt; j += 512) {       // coalesced emit
        int b = sbkt[j];
        int p = gdelta[b] + j;                 // == gbase[b] + (j - lbase[b])
        if (p < (b + 1) * CAP) ebuf[p] = sval[j];  // overflow guard
    }
}

// One block per bucket, 1024 threads: stage edges into LDS once, fine hist +
// scan (lanes<256, uniform barriers) + place from LDS.
__global__ void __launch_bounds__(1024) k_bucket(
        const int* __restrict__ ebuf, const int* __restrict__ gcur,
        int* __restrict__ begA, int* __restrict__ endA, int* __restrict__ ssrc,
        float* __restrict__ dis, int n) {
    __shared__ int ev[CAP];            // 36 KB staged bucket
    __shared__ int hist[256];
    __shared__ int sc[256];
    const int b = blockIdx.x, t = threadIdx.x;
    const int base = b * CAP;
    const int cnt = min(gcur[b] - base, CAP);
    if (t < 256) hist[t] = 0;
    __syncthreads();
    for (int j = t; j < cnt; j += 1024) {
        int v = ebuf[base + j];
        ev[j] = v;
        atomicAdd(&hist[v >> 17], 1);
    }
    __syncthreads();
    int v = 0;
    if (t < 256) { v = hist[t]; sc[t] = v; }
    __syncthreads();
    for (int off = 1; off < 256; off <<= 1) {
        int add = 0;
        if (t < 256 && t >= off) add = sc[t - off];
        __syncthreads();
        if (t < 256) sc[t] += add;
        __syncthreads();
    }
    if (t < 256) {
        int excl = sc[t] - v;
        int node = (b << CB) + t;
        if (node < n) {
            begA[node] = base + excl;
            endA[node] = base + excl + v;
            dis[node] = rsqrtf((float)(v + 1));
        }
        hist[t] = excl;  // local cursor
    }
    __syncthreads();
    for (int j = t; j < cnt; j += 1024) {
        int val = ev[j];
        int p = atomicAdd(&hist[val >> 17], 1);
        ssrc[base + p] = val & 0x1FFFF;    // scattered 4B: MUST stay cached (R10)
    }
}

// g[N,16] (fp16) = dis[row] * (x[N,128] @ W1[128,16]).
// 8 lanes/row: coalesced float4 reads, butterfly reduce, 32B coalesced store.
__global__ void k_gemm1(const float* __restrict__ x, const float* __restrict__ W1,
                        const float* __restrict__ dis, __half* __restrict__ gh, int n) {
    __shared__ float wt[16 * 128];
    for (int t = threadIdx.x; t < 2048; t += blockDim.x) {
        int j = t >> 7, k = t & 127;
        wt[t] = W1[k * 16 + j];
    }
    __syncthreads();
    int t = blockIdx.x * blockDim.x + threadIdx.x;
    if (t >= n * 8) return;
    int r = t >> 3, l = t & 7;
    const float4* x4 = (const float4*)x;
    const float4* w4 = (const float4*)wt;
    float4 va = x4[(size_t)r * 32 + l];
    float4 vb = x4[(size_t)r * 32 + l + 8];
    float4 vc = x4[(size_t)r * 32 + l + 16];
    float4 vd = x4[(size_t)r * 32 + l + 24];
    float acc[16];
#pragma unroll
    for (int j = 0; j < 16; ++j) {
        float4 wa = w4[j * 32 + l];
        float4 wb = w4[j * 32 + l + 8];
        float4 wc = w4[j * 32 + l + 16];
        float4 wd = w4[j * 32 + l + 24];
        acc[j] = va.x * wa.x + va.y * wa.y + va.z * wa.z + va.w * wa.w
               + vb.x * wb.x + vb.y * wb.y + vb.z * wb.z + vb.w * wb.w
               + vc.x * wc.x + vc.y * wc.y + vc.z * wc.z + vc.w * wc.w
               + vd.x * wd.x + vd.y * wd.y + vd.z * wd.z + vd.w * wd.w;
    }
#pragma unroll
    for (int j = 0; j < 16; ++j) {
#pragma unroll
        for (int m = 4; m >= 1; m >>= 1) acc[j] += __shfl_xor(acc[j], m, 8);
    }
    float d = dis[r];
    __half2 hh = __floats2half2_rn(d * acc[2 * l], d * acc[2 * l + 1]);
    ((__half2*)gh)[(size_t)r * 8 + l] = hh;  // 8 lanes -> 32B coalesced
}

// Unpack a 16B load (4x half2 = 8 fp16) and accumulate into 8 fp32 lanes.
__device__ inline void h8acc(float4 r, float* a) {
    const __half2* h = (const __half2*)&r;
#pragma unroll
    for (int k = 0; k < 4; ++k) {
        float2 f = __half22float2(h[k]);
        a[2 * k] += f.x;
        a[2 * k + 1] += f.y;
    }
}

// 2 threads/node, 16B (float4 = 8 fp16) reads: same useful bytes as the 4-lane
// version but half the VMEM instructions and HALF the L2 sector traffic
// (random requests are 64B-sector-granular). Rows are 32B-aligned so a 16B
// load never straddles a line. Edge loop unrolled x8 for loads in flight.
__global__ void k_gather1(const int* __restrict__ begA, const int* __restrict__ endA,
                          const int* __restrict__ ssrc,
                          const float4* __restrict__ g8, const float* __restrict__ dis,
                          const float* __restrict__ b1, const float* __restrict__ W2,
                          float* __restrict__ tbuf, int n) {
    int t = blockIdx.x * blockDim.x + threadIdx.x;
    if (t >= n * 2) return;
    int i = t >> 1, l = t & 1;
    float di = dis[i];
    int beg = begA[i], end = endA[i];
    float a[8], b[8];                           // features 8l .. 8l+7
    {
        float4 s = g8[(size_t)i * 2 + l];       // self-loop
        const __half2* h = (const __half2*)&s;
#pragma unroll
        for (int k = 0; k < 4; ++k) {
            float2 f = __half22float2(h[k]);
            a[2 * k] = f.x;
            a[2 * k + 1] = f.y;
            b[2 * k] = 0.f;
            b[2 * k + 1] = 0.f;
        }
    }
    int e = beg;
    for (; e + 8 <= end; e += 8) {
        int s0 = ssrc[e + 0], s1 = ssrc[e + 1], s2 = ssrc[e + 2], s3 = ssrc[e + 3];
        int s4 = ssrc[e + 4], s5 = ssrc[e + 5], s6 = ssrc[e + 6], s7 = ssrc[e + 7];
        float4 r0 = g8[(size_t)s0 * 2 + l];
        float4 r1 = g8[(size_t)s1 * 2 + l];
        float4 r2 = g8[(size_t)s2 * 2 + l];
        float4 r3 = g8[(size_t)s3 * 2 + l];
        float4 r4 = g8[(size_t)s4 * 2 + l];
        float4 r5 = g8[(size_t)s5 * 2 + l];
        float4 r6 = g8[(size_t)s6 * 2 + l];
        float4 r7 = g8[(size_t)s7 * 2 + l];
        h8acc(r0, a); h8acc(r1, b);
        h8acc(r2, a); h8acc(r3, b);
        h8acc(r4, a); h8acc(r5, b);
        h8acc(r6, a); h8acc(r7, b);
    }
    for (; e < end; ++e) {
        float4 r = g8[(size_t)ssrc[e] * 2 + l];
        h8acc(r, a);
    }
    int f = l * 8;
    float u = 0.f;
#pragma unroll
    for (int k = 0; k < 8; ++k)
        u += fmaxf(di * (a[k] + b[k]) + b1[f + k], 0.f) * W2[f + k];
    u += __shfl_xor(u, 1, 2);
    if (l == 0) tbuf[i] = di * u;
}

// 8 threads/node, lane-strided edges (coalesced ssrc), unroll x4 for MLP:
// out[i] = dis[i] * (sum_e t[src] + t[i]) + b2
__global__ void k_gather2(const int* __restrict__ begA, const int* __restrict__ endA,
                          const int* __restrict__ ssrc,
                          const float* __restrict__ tbuf, const float* __restrict__ dis,
                          const float* __restrict__ b2, float* __restrict__ out, int n) {
    int t = blockIdx.x * blockDim.x + threadIdx.x;
    if (t >= n * 8) return;
    int i = t >> 3, l = t & 7;
    int beg = begA[i], end = endA[i];
    float acc = (l == 0) ? tbuf[i] : 0.f;
    float acc1 = 0.f;
    int e = beg + l;
    for (; e + 24 < end; e += 32) {
        int s0 = ssrc[e], s1 = ssrc[e + 8], s2 = ssrc[e + 16], s3 = ssrc[e + 24];
        float v0 = tbuf[s0], v1 = tbuf[s1], v2 = tbuf[s2], v3 = tbuf[s3];
        acc += v0; acc1 += v1; acc += v2; acc1 += v3;
    }
    for (; e < end; e += 8) acc += tbuf[ssrc[e]];
    acc += acc1;
#pragma unroll
    for (int m = 4; m >= 1; m >>= 1) acc += __shfl_xor(acc, m, 8);
    if (l == 0) out[i] = dis[i] * acc + b2[0];
}

extern "C" void kernel_launch(void* const* d_in, const int* in_sizes, int n_in,
                              void* d_out, int out_size, void* d_ws, size_t ws_size,
                              hipStream_t stream) {
    const float* x  = (const float*)d_in[0];
    const int*   ei = (const int*)d_in[1];
    const float* W1 = (const float*)d_in[2];
    const float* b1 = (const float*)d_in[3];
    const float* W2 = (const float*)d_in[4];
    const float* b2 = (const float*)d_in[5];
    float* out = (float*)d_out;

    const int N = in_sizes[0] / 128;   // 100000
    const int E = in_sizes[1] / 2;     // 3200000
    const int* row = ei;        // edge_index[0] = source
    const int* col = ei + E;    // edge_index[1] = target
    const int NB = (N + 255) >> CB;    // coarse buckets (391)
    const size_t PADE = (size_t)NB * CAP;  // padded edge capacity

    // workspace (4B units): ebuf[PADE] (aliased by gh fp16 after k_bucket) |
    // ssrc[PADE] | dis[N] | tbuf[N] | begA[N] | endA[N] | gcur[512]
    size_t bigsz = PADE > (size_t)N * 8 ? PADE : (size_t)N * 8;
    int*    ebuf = (int*)d_ws;
    __half* gh   = (__half*)d_ws;      // aliases ebuf (dead before k_gemm1)
    int*    ssrc = (int*)d_ws + bigsz;
    float*  dis  = (float*)(ssrc + PADE);
    float*  tbuf = dis + N;
    int*    begA = (int*)(tbuf + N);
    int*    endA = begA + N;
    int*    gcur = endA + N;

    auto cdiv = [](int a, int b) { return (a + b - 1) / b; };

    k_init_gcur<<<cdiv(NB, 256),    256,  0, stream>>>(gcur, NB);
    k_partition<<<cdiv(E, TILE),    512,  0, stream>>>(row, col, gcur, ebuf, E, NB);
    k_bucket   <<<NB,               1024, 0, stream>>>(ebuf, gcur, begA, endA, ssrc, dis, N);
    k_gemm1    <<<cdiv(N * 8, 256), 256,  0, stream>>>(x, W1, dis, gh, N);
    k_gather1  <<<cdiv(N * 2, 256), 256,  0, stream>>>(begA, endA, ssrc, (const float4*)gh,
                                                       dis, b1, W2, tbuf, N);
    k_gather2  <<<cdiv(N * 8, 256), 256,  0, stream>>>(begA, endA, ssrc, tbuf, dis, b2, out, N);
}